// Round 12
// baseline (64.954 us; speedup 1.0000x reference)
//
#include <hip/hip_runtime.h>
#include <hip/hip_fp16.h>
#include <math.h>

#define EPSF 1e-15f
#define MAX_TANH_F (1.0f - 1e-5f)
#define KDIM 512
#define NOUT 256
#define BM 32
#define BK 64

// Raw barrier: waits only for LDS ops (ds_write visibility), leaves global
// loads (vmcnt) in flight across the barrier.
#define BAR_LDS() asm volatile("s_waitcnt lgkmcnt(0)\n\ts_barrier" ::: "memory")

typedef __attribute__((ext_vector_type(8))) __bf16 bf16x8;
typedef __attribute__((ext_vector_type(8))) _Float16 f16x8;
typedef __attribute__((ext_vector_type(4))) float f32x4;

__device__ __forceinline__ float artanh_clip(float x) {
    x = fminf(fmaxf(x, -MAX_TANH_F), MAX_TANH_F);
    return atanhf(x);
}

__device__ __forceinline__ void unpack2h(unsigned int u, float& a, float& b) {
    __half2 hh = __builtin_bit_cast(__half2, u);
    a = __low2float(hh);
    b = __high2float(hh);
}

__device__ __forceinline__ bf16x8 cvt8(const float4& a, const float4& b) {
    bf16x8 r;
    r[0] = (__bf16)a.x; r[1] = (__bf16)a.y; r[2] = (__bf16)a.z; r[3] = (__bf16)a.w;
    r[4] = (__bf16)b.x; r[5] = (__bf16)b.y; r[6] = (__bf16)b.z; r[7] = (__bf16)b.w;
    return r;
}
__device__ __forceinline__ float sq8(const float4& a, const float4& b) {
    return a.x*a.x + a.y*a.y + a.z*a.z + a.w*a.w
         + b.x*b.x + b.y*b.y + b.z*b.z + b.w*b.w;
}

// P2: Wp[s][nt][lane][8] bf16 B-fragment layout (col=nt*16+(lane&15), k=s*32+(lane>>4)*8+j)
__global__ __launch_bounds__(64) void prep_w_kernel(
    const float* __restrict__ W, unsigned int* __restrict__ Wp)
{
    const int b = blockIdx.x;       // b = s*16 + nt, 256 blocks
    const int l = threadIdx.x;      // 64 lanes
    const int k0 = (b >> 4) * 32 + (l >> 4) * 8;
    const int col = (b & 15) * 16 + (l & 15);
    bf16x8 v;
    #pragma unroll
    for (int j = 0; j < 8; ++j) v[j] = (__bf16)W[(size_t)(k0 + j) * NOUT + col];
    *(uint4*)(Wp + ((size_t)b * 64 + l) * 4) = __builtin_bit_cast(uint4, v);
}

// K1 (R11-exact): fused stage+GEMM+mobius_matvec.
__global__ __launch_bounds__(256) void gemm_mobius_kernel(
    const float* __restrict__ feat, const uint4* __restrict__ Wp,
    __half* __restrict__ h, float* __restrict__ hnorm2,
    float scale, int N)
{
    __shared__ float lds_a[2][BM * BK];   // 16 KB total
    __shared__ float sred[4][BM];
    __shared__ float sfac[BM];
    __shared__ float sxn2[BM];

    const int tid  = threadIdx.x;
    const int wave = tid >> 6;
    const int lane = tid & 63;
    const int rr   = lane & 15;
    const int g    = lane >> 4;
    const int base = blockIdx.x * BM;

    const int srow = tid >> 3;
    const int sk   = (tid & 7) * 8;
    const int grow = base + srow;
    const float* gsrc = feat + (size_t)(grow < N ? grow : N - 1) * KDIM + sk;
    const int wslot0 = (((tid & 7) * 2)     ^ (srow & 15)) * 4;
    const int wslot1 = (((tid & 7) * 2 + 1) ^ (srow & 15)) * 4;

    f32x4 acc[2][4];
    #pragma unroll
    for (int hh = 0; hh < 2; ++hh)
        #pragma unroll
        for (int t = 0; t < 4; ++t) acc[hh][t] = (f32x4){0.f, 0.f, 0.f, 0.f};

    const uint4* wp = Wp + (size_t)wave * 4 * 64 + lane;

    uint4 B[2][4];
    #pragma unroll
    for (int p = 0; p < 2; ++p)
        #pragma unroll
        for (int t = 0; t < 4; ++t)
            B[p][t] = wp[((size_t)p * 16 + t) * 64];

    float4 t0a = *(const float4*)(gsrc);
    float4 t0b = *(const float4*)(gsrc + 4);
    float4 navOa = *(const float4*)(gsrc + 1 * BK);
    float4 navOb = *(const float4*)(gsrc + 1 * BK + 4);
    float4 navEa = *(const float4*)(gsrc + 2 * BK);
    float4 navEb = *(const float4*)(gsrc + 2 * BK + 4);
    {
        float* d = &lds_a[0][srow * BK];
        *(float4*)(d + wslot0) = t0a;
        *(float4*)(d + wslot1) = t0b;
    }
    BAR_LDS();

    float xs0 = 0.f, xs1 = 0.f;

    #pragma unroll
    for (int kk = 0; kk < 8; ++kk) {
        if (kk < 7) {
            float* d = &lds_a[(kk + 1) & 1][srow * BK];
            if ((kk & 1) == 0) {
                *(float4*)(d + wslot0) = navOa;
                *(float4*)(d + wslot1) = navOb;
                if (kk + 3 < 8) {
                    navOa = *(const float4*)(gsrc + (kk + 3) * BK);
                    navOb = *(const float4*)(gsrc + (kk + 3) * BK + 4);
                }
            } else {
                *(float4*)(d + wslot0) = navEa;
                *(float4*)(d + wslot1) = navEb;
                if (kk + 3 < 8) {
                    navEa = *(const float4*)(gsrc + (kk + 3) * BK);
                    navEb = *(const float4*)(gsrc + (kk + 3) * BK + 4);
                }
            }
        }

        const float* buf = lds_a[kk & 1];
        #pragma unroll
        for (int ss = 0; ss < 2; ++ss) {
            const int s = kk * 2 + ss;
            const int ls0 = ((ss * 8 + g * 2)     ^ rr) * 4;
            const int ls1 = ((ss * 8 + g * 2 + 1) ^ rr) * 4;
            float4 a00 = *(const float4*)(buf + rr * BK + ls0);
            float4 a01 = *(const float4*)(buf + rr * BK + ls1);
            float4 a10 = *(const float4*)(buf + (16 + rr) * BK + ls0);
            float4 a11 = *(const float4*)(buf + (16 + rr) * BK + ls1);
            xs0 += sq8(a00, a01);
            xs1 += sq8(a10, a11);
            bf16x8 ah0 = cvt8(a00, a01);
            bf16x8 ah1 = cvt8(a10, a11);
            uint4 b0 = B[s & 1][0], b1 = B[s & 1][1], b2 = B[s & 1][2], b3 = B[s & 1][3];
            if (s + 2 < 16) {
                #pragma unroll
                for (int t = 0; t < 4; ++t)
                    B[s & 1][t] = wp[((size_t)(s + 2) * 16 + t) * 64];
            }
            acc[0][0] = __builtin_amdgcn_mfma_f32_16x16x32_bf16(ah0, __builtin_bit_cast(bf16x8, b0), acc[0][0], 0, 0, 0);
            acc[1][0] = __builtin_amdgcn_mfma_f32_16x16x32_bf16(ah1, __builtin_bit_cast(bf16x8, b0), acc[1][0], 0, 0, 0);
            acc[0][1] = __builtin_amdgcn_mfma_f32_16x16x32_bf16(ah0, __builtin_bit_cast(bf16x8, b1), acc[0][1], 0, 0, 0);
            acc[1][1] = __builtin_amdgcn_mfma_f32_16x16x32_bf16(ah1, __builtin_bit_cast(bf16x8, b1), acc[1][1], 0, 0, 0);
            acc[0][2] = __builtin_amdgcn_mfma_f32_16x16x32_bf16(ah0, __builtin_bit_cast(bf16x8, b2), acc[0][2], 0, 0, 0);
            acc[1][2] = __builtin_amdgcn_mfma_f32_16x16x32_bf16(ah1, __builtin_bit_cast(bf16x8, b2), acc[1][2], 0, 0, 0);
            acc[0][3] = __builtin_amdgcn_mfma_f32_16x16x32_bf16(ah0, __builtin_bit_cast(bf16x8, b3), acc[0][3], 0, 0, 0);
            acc[1][3] = __builtin_amdgcn_mfma_f32_16x16x32_bf16(ah1, __builtin_bit_cast(bf16x8, b3), acc[1][3], 0, 0, 0);
        }
        BAR_LDS();
    }

    xs0 += __shfl_xor(xs0, 16); xs0 += __shfl_xor(xs0, 32);
    xs1 += __shfl_xor(xs1, 16); xs1 += __shfl_xor(xs1, 32);
    if (wave == 0 && lane < 16) { sxn2[lane] = xs0; sxn2[16 + lane] = xs1; }

    #pragma unroll
    for (int hh = 0; hh < 2; ++hh) {
        #pragma unroll
        for (int r = 0; r < 4; ++r) {
            float p = 0.f;
            #pragma unroll
            for (int t = 0; t < 4; ++t) p += acc[hh][t][r] * acc[hh][t][r];
            p += __shfl_xor(p, 1);
            p += __shfl_xor(p, 2);
            p += __shfl_xor(p, 4);
            p += __shfl_xor(p, 8);
            if (rr == 0) sred[wave][hh * 16 + g * 4 + r] = p;
        }
    }
    __syncthreads();

    if (tid < BM) {
        const int r = tid;
        const float mx2 = sred[0][r] + sred[1][r] + sred[2][r] + sred[3][r];
        const float mxn = fmaxf(scale * sqrtf(mx2), EPSF);
        const float xn  = fmaxf(scale * sqrtf(sxn2[r]), EPSF);
        float ttv = tanhf(mxn / xn * artanh_clip(xn));
        float fc  = ttv * scale / mxn;
        if (mxn <= 1e-10f) { fc = 0.f; ttv = 0.f; }
        sfac[r] = fc;
        if (base + r < N) hnorm2[base + r] = ttv * ttv;
    }
    __syncthreads();

    #pragma unroll
    for (int hh = 0; hh < 2; ++hh) {
        #pragma unroll
        for (int r = 0; r < 4; ++r) {
            const int row_r = base + hh * 16 + g * 4 + r;
            if (row_r < N) {
                const float fc = sfac[hh * 16 + g * 4 + r];
                __half* hr = h + (size_t)row_r * NOUT + wave * 64 + rr;
                #pragma unroll
                for (int t = 0; t < 4; ++t) hr[t * 16] = __float2half(acc[hh][t][r] * fc);
            }
        }
    }
}

// K2 (Gram rewrite): mobius scan as scalar alpha-recurrence over the Gram
// matrix of the 16 gathered rows (mobius_add output is a linear combination
// of its inputs). One wave per output row. G = M*M^T via 8 f16 MFMAs
// (fragment serves as both A and B). Final c = sum(alpha_q * m_q) via
// L2-warm re-read in a coalesced per-lane-4-comps layout.
__global__ __launch_bounds__(256) void aggregate_kernel(
    const __half* __restrict__ h, const float* __restrict__ hnorm2,
    const int* __restrict__ src, const float* __restrict__ bias,
    float* __restrict__ out, float scale, int N)
{
    const int wave = threadIdx.x >> 6;
    const int lane = threadIdx.x & 63;
    const int n = blockIdx.x * 4 + wave;
    if (n >= N) return;
    const int q = lane & 15;      // row of this lane's fragment / G column
    const int g = lane >> 4;      // k-quarter group / G row block

    const int sidx = src[(size_t)n * 16 + q];   // lanes 16.. duplicate lanes 0-15
    const float y2v = hnorm2[sidx];

    // A/B fragment for row q: 8 halfs at k = s*32 + g*8 .. +7
    const char* mrow = (const char*)(h + (size_t)sidx * NOUT) + g * 16;
    uint4 f0 = *(const uint4*)(mrow + 0 * 64);
    uint4 f1 = *(const uint4*)(mrow + 1 * 64);
    uint4 f2 = *(const uint4*)(mrow + 2 * 64);
    uint4 f3 = *(const uint4*)(mrow + 3 * 64);
    uint4 f4 = *(const uint4*)(mrow + 4 * 64);
    uint4 f5 = *(const uint4*)(mrow + 5 * 64);
    uint4 f6 = *(const uint4*)(mrow + 6 * 64);
    uint4 f7 = *(const uint4*)(mrow + 7 * 64);

    // Gram: G[g*4+r][q] in Gm[r]
    f32x4 Gm = (f32x4){0.f, 0.f, 0.f, 0.f};
    Gm = __builtin_amdgcn_mfma_f32_16x16x32_f16(__builtin_bit_cast(f16x8, f0), __builtin_bit_cast(f16x8, f0), Gm, 0, 0, 0);
    Gm = __builtin_amdgcn_mfma_f32_16x16x32_f16(__builtin_bit_cast(f16x8, f1), __builtin_bit_cast(f16x8, f1), Gm, 0, 0, 0);
    Gm = __builtin_amdgcn_mfma_f32_16x16x32_f16(__builtin_bit_cast(f16x8, f2), __builtin_bit_cast(f16x8, f2), Gm, 0, 0, 0);
    Gm = __builtin_amdgcn_mfma_f32_16x16x32_f16(__builtin_bit_cast(f16x8, f3), __builtin_bit_cast(f16x8, f3), Gm, 0, 0, 0);
    Gm = __builtin_amdgcn_mfma_f32_16x16x32_f16(__builtin_bit_cast(f16x8, f4), __builtin_bit_cast(f16x8, f4), Gm, 0, 0, 0);
    Gm = __builtin_amdgcn_mfma_f32_16x16x32_f16(__builtin_bit_cast(f16x8, f5), __builtin_bit_cast(f16x8, f5), Gm, 0, 0, 0);
    Gm = __builtin_amdgcn_mfma_f32_16x16x32_f16(__builtin_bit_cast(f16x8, f6), __builtin_bit_cast(f16x8, f6), Gm, 0, 0, 0);
    Gm = __builtin_amdgcn_mfma_f32_16x16x32_f16(__builtin_bit_cast(f16x8, f7), __builtin_bit_cast(f16x8, f7), Gm, 0, 0, 0);

    // alpha-scan: lane (q,g) owns alpha[g*4 .. g*4+3] (replicated across q)
    float a0 = (g == 0) ? 1.f : 0.f;
    float a1 = 0.f, a2 = 0.f, a3 = 0.f;
    float c2 = __shfl(y2v, 0);

    #pragma unroll
    for (int j = 1; j < 16; ++j) {
        // xy = <c, m_j> = sum_i alpha_i * G[i][j]; this lane's partial over its 4 rows
        float p = fmaf(a0, Gm[0], fmaf(a1, Gm[1], fmaf(a2, Gm[2], a3 * Gm[3])));
        p += __shfl_xor(p, 16);
        p += __shfl_xor(p, 32);
        const float xy  = __shfl(p, j);        // column j's dot (lane j: q=j,g=0)
        const float y2j = __shfl(y2v, j);
        const float A = 1.f + 2.f * xy + y2j;
        const float Bc = 1.f - c2;
        const float den = fmaxf(1.f + 2.f * xy + c2 * y2j, EPSF);
        const float inv = __builtin_amdgcn_rcpf(den);
        const float Ai = A * inv, Bi = Bc * inv;
        a0 *= Ai; a1 *= Ai; a2 *= Ai; a3 *= Ai;
        if (g == (j >> 2)) {
            if ((j & 3) == 0)      a0 = Bi;
            else if ((j & 3) == 1) a1 = Bi;
            else if ((j & 3) == 2) a2 = Bi;
            else                   a3 = Bi;
        }
        c2 = fmaxf((A * A * c2 + 2.f * A * Bc * xy + Bc * Bc * y2j) * (inv * inv), 0.f);
    }

    // rst *= scale (fold into alpha and c2)
    a0 *= scale; a1 *= scale; a2 *= scale; a3 *= scale;
    c2 *= scale * scale;

    // final c = sum_q alpha_q * m_q, lane owns comps lane*4 .. lane*4+3
    float cv0 = 0.f, cv1 = 0.f, cv2 = 0.f, cv3 = 0.f;
    #pragma unroll
    for (int q2 = 0; q2 < 16; ++q2) {
        const int srcl = (q2 >> 2) * 16;       // a lane holding alpha[q2]
        float aq;
        if ((q2 & 3) == 0)      aq = __shfl(a0, srcl);
        else if ((q2 & 3) == 1) aq = __shfl(a1, srcl);
        else if ((q2 & 3) == 2) aq = __shfl(a2, srcl);
        else                    aq = __shfl(a3, srcl);
        const int iq = __shfl(sidx, q2);
        const uint2 hv = *(const uint2*)(h + (size_t)iq * NOUT + lane * 4);
        float w0, w1, w2, w3;
        unpack2h(hv.x, w0, w1);
        unpack2h(hv.y, w2, w3);
        cv0 = fmaf(aq, w0, cv0);
        cv1 = fmaf(aq, w1, cv1);
        cv2 = fmaf(aq, w2, cv2);
        cv3 = fmaf(aq, w3, cv3);
    }

    // mobius_add(c, bias)
    const float4 b4 = *(const float4*)(bias + lane * 4);
    float bp = b4.x*b4.x + b4.y*b4.y + b4.z*b4.z + b4.w*b4.w;
    float xp = cv0*b4.x + cv1*b4.y + cv2*b4.z + cv3*b4.w;
    #pragma unroll
    for (int d = 1; d < 64; d <<= 1) {
        bp += __shfl_xor(bp, d);
        xp += __shfl_xor(xp, d);
    }
    const float bb = bp, xy = xp;
    const float A = 1.f + 2.f * xy + bb;
    const float Bc = 1.f - c2;
    const float den = fmaxf(1.f + 2.f * xy + c2 * bb, EPSF);
    const float inv = 1.f / den;
    float r0 = fmaf(A, cv0, Bc * b4.x) * inv;
    float r1 = fmaf(A, cv1, Bc * b4.y) * inv;
    float r2 = fmaf(A, cv2, Bc * b4.z) * inv;
    float r3 = fmaf(A, cv3, Bc * b4.w) * inv;
    const float rn2 = fmaxf((A * A * c2 + 2.f * A * Bc * xy + Bc * Bc * bb) * (inv * inv), 0.f);

    // expmap0(relu(logmap0(.)))
    const float rn = fmaxf(sqrtf(rn2), EPSF);
    const float lf = artanh_clip(rn) / rn;
    float u0 = fmaxf(r0 * lf, 0.f);
    float u1 = fmaxf(r1 * lf, 0.f);
    float u2 = fmaxf(r2 * lf, 0.f);
    float u3 = fmaxf(r3 * lf, 0.f);
    float up = u0*u0 + u1*u1 + u2*u2 + u3*u3;
    #pragma unroll
    for (int d = 1; d < 64; d <<= 1) up += __shfl_xor(up, d);
    const float un = fmaxf(sqrtf(up), EPSF);
    const float ef = tanhf(un) / un;

    float4 o;
    o.x = u0 * ef; o.y = u1 * ef; o.z = u2 * ef; o.w = u3 * ef;
    *(float4*)(out + (size_t)n * NOUT + lane * 4) = o;
}

extern "C" void kernel_launch(void* const* d_in, const int* in_sizes, int n_in,
                              void* d_out, int out_size, void* d_ws, size_t ws_size,
                              hipStream_t stream) {
    const float* feat   = (const float*)d_in[0];
    const float* weight = (const float*)d_in[1];
    const float* bias   = (const float*)d_in[2];
    const int*   src    = (const int*)d_in[3];

    const int OUT = in_sizes[2];            // 256
    const int IN  = in_sizes[1] / OUT;      // 512
    const int N   = in_sizes[0] / IN;       // 20000
    const int DEG = in_sizes[3] / N;        // 16
    (void)IN; (void)DEG; (void)out_size; (void)ws_size; (void)n_in;

    const float scale = 1.0f / sqrtf((float)DEG);

    // ws layout: h fp16 (N*256*2 B) | hnorm2 (N f32) | Wp (256 KB)
    char* ws = (char*)d_ws;
    __half* h     = (__half*)ws;
    float* hnorm2 = (float*)(ws + (size_t)N * NOUT * 2);
    unsigned int* Wp = (unsigned int*)(ws + (size_t)N * NOUT * 2 + (size_t)N * 4);

    float* out = (float*)d_out;

    const int nbm = (N + BM - 1) / BM;      // 625

    hipLaunchKernelGGL(prep_w_kernel, dim3(256), dim3(64), 0, stream,
                       weight, Wp);
    hipLaunchKernelGGL(gemm_mobius_kernel, dim3(nbm), dim3(256), 0, stream,
                       feat, (const uint4*)Wp, h, hnorm2, scale, N);
    hipLaunchKernelGGL(aggregate_kernel, dim3((N + 3) / 4), dim3(256), 0, stream,
                       h, hnorm2, src, bias, out, scale, N);
}

// Round 13
// 51.717 us; speedup vs baseline: 1.2560x; 1.2560x over previous
//
#include <hip/hip_runtime.h>
#include <hip/hip_fp16.h>
#include <math.h>

#define EPSF 1e-15f
#define MAX_TANH_F (1.0f - 1e-5f)
#define KDIM 512
#define NOUT 256
#define BM 32
#define BK 64

typedef __attribute__((ext_vector_type(8))) __bf16 bf16x8;
typedef __attribute__((ext_vector_type(4))) float f32x4;

// Counted barrier: drain the 2 outstanding global_load_lds (issued before the
// 8 B-prefetch loads, order pinned by sched_barrier) but leave the B loads in
// flight across the barrier (T4: never vmcnt(0) in the main loop).
#define BAR_TILE() asm volatile("s_waitcnt vmcnt(8) lgkmcnt(0)\n\ts_barrier" ::: "memory")

__device__ __forceinline__ void gload_lds16(const float* g, float* l) {
    __builtin_amdgcn_global_load_lds(
        (const __attribute__((address_space(1))) void*)g,
        (__attribute__((address_space(3))) void*)l, 16, 0, 0);
}

__device__ __forceinline__ float artanh_clip(float x) {
    x = fminf(fmaxf(x, -MAX_TANH_F), MAX_TANH_F);
    return atanhf(x);
}

__device__ __forceinline__ void unpack2h(unsigned int u, float& a, float& b) {
    __half2 hh = __builtin_bit_cast(__half2, u);
    a = __low2float(hh);
    b = __high2float(hh);
}

__device__ __forceinline__ bf16x8 cvt8(const float4& a, const float4& b) {
    bf16x8 r;
    r[0] = (__bf16)a.x; r[1] = (__bf16)a.y; r[2] = (__bf16)a.z; r[3] = (__bf16)a.w;
    r[4] = (__bf16)b.x; r[5] = (__bf16)b.y; r[6] = (__bf16)b.z; r[7] = (__bf16)b.w;
    return r;
}
__device__ __forceinline__ float sq8(const float4& a, const float4& b) {
    return a.x*a.x + a.y*a.y + a.z*a.z + a.w*a.w
         + b.x*b.x + b.y*b.y + b.z*b.z + b.w*b.w;
}

// P2: Wp[s][nt][lane][8] bf16 B-fragment layout (col=nt*16+(lane&15), k=s*32+(lane>>4)*8+j)
__global__ __launch_bounds__(64) void prep_w_kernel(
    const float* __restrict__ W, unsigned int* __restrict__ Wp)
{
    const int b = blockIdx.x;       // b = s*16 + nt, 256 blocks
    const int l = threadIdx.x;      // 64 lanes
    const int k0 = (b >> 4) * 32 + (l >> 4) * 8;
    const int col = (b & 15) * 16 + (l & 15);
    bf16x8 v;
    #pragma unroll
    for (int j = 0; j < 8; ++j) v[j] = (__bf16)W[(size_t)(k0 + j) * NOUT + col];
    *(uint4*)(Wp + ((size_t)b * 64 + l) * 4) = __builtin_bit_cast(uint4, v);
}

// K1: fused stage+GEMM+mobius_matvec. Block = 32 rows x 256 cols, 4 waves;
// wave = 32 rows x 64 cols (16 MFMA/kk). A staged via global_load_lds width-16
// (LDS linear; XOR swizzle folded into the per-lane GLOBAL source address),
// double-buffered, counted-vmcnt barrier. B: reg rolling s+2 prefetch.
__global__ __launch_bounds__(256) void gemm_mobius_kernel(
    const float* __restrict__ feat, const uint4* __restrict__ Wp,
    __half* __restrict__ h, float* __restrict__ hnorm2,
    float scale, int N)
{
    __shared__ float lds_a[2][BM * BK];   // 16 KB total
    __shared__ float sred[4][BM];
    __shared__ float sfac[BM];
    __shared__ float sxn2[BM];

    const int tid  = threadIdx.x;
    const int wave = tid >> 6;
    const int lane = tid & 63;
    const int rr   = lane & 15;
    const int g    = lane >> 4;
    const int base = blockIdx.x * BM;

    // global_load_lds mapping: instruction j (0,1) for wave w stages rows
    // j*16 + w*4 + (lane>>4); lane's 16B covers float4-slot s16 = lane&15 of
    // that row, sourced from feat column slot (s16 ^ (row&15)) -> LDS stays
    // linear, data lands pre-swizzled for the ds_read XOR pattern below.
    const int row0  = wave * 4 + (lane >> 4);       // j=0 row (0..15)
    const int row1  = 16 + row0;                    // j=1 row (16..31)
    const int s16x  = (lane & 15) ^ (row0 & 15);    // row1&15 == row0&15
    const int gr0 = base + row0 < N ? base + row0 : N - 1;
    const int gr1 = base + row1 < N ? base + row1 : N - 1;
    const float* gs0 = feat + (size_t)gr0 * KDIM + s16x * 4;
    const float* gs1 = feat + (size_t)gr1 * KDIM + s16x * 4;

    f32x4 acc[2][4];
    #pragma unroll
    for (int hh = 0; hh < 2; ++hh)
        #pragma unroll
        for (int t = 0; t < 4; ++t) acc[hh][t] = (f32x4){0.f, 0.f, 0.f, 0.f};

    const uint4* wp = Wp + (size_t)wave * 4 * 64 + lane;

    // prologue: A tile 0 via gload_lds, then B s=0,1 into regs
    gload_lds16(gs0, &lds_a[0][(wave * 4) * BK]);
    gload_lds16(gs1, &lds_a[0][(16 + wave * 4) * BK]);
    __builtin_amdgcn_sched_barrier(0);

    uint4 B[2][4];
    #pragma unroll
    for (int p = 0; p < 2; ++p)
        #pragma unroll
        for (int t = 0; t < 4; ++t)
            B[p][t] = wp[((size_t)p * 16 + t) * 64];

    BAR_TILE();   // drains the 2 gloads (oldest); B loads stay in flight

    float xs0 = 0.f, xs1 = 0.f;

    #pragma unroll
    for (int kk = 0; kk < 8; ++kk) {
        // stage tile kk+1 directly to the other LDS buffer (DMA, no VGPRs).
        // Safe: barrier at end of kk-1 ensured no wave still reads it.
        if (kk < 7) {
            float* db = &lds_a[(kk + 1) & 1][0];
            gload_lds16(gs0 + (kk + 1) * BK, db + (wave * 4) * BK);
            gload_lds16(gs1 + (kk + 1) * BK, db + (16 + wave * 4) * BK);
            __builtin_amdgcn_sched_barrier(0);
        }

        const float* buf = lds_a[kk & 1];
        #pragma unroll
        for (int ss = 0; ss < 2; ++ss) {
            const int s = kk * 2 + ss;
            const int ls0 = ((ss * 8 + g * 2)     ^ rr) * 4;
            const int ls1 = ((ss * 8 + g * 2 + 1) ^ rr) * 4;
            float4 a00 = *(const float4*)(buf + rr * BK + ls0);
            float4 a01 = *(const float4*)(buf + rr * BK + ls1);
            float4 a10 = *(const float4*)(buf + (16 + rr) * BK + ls0);
            float4 a11 = *(const float4*)(buf + (16 + rr) * BK + ls1);
            xs0 += sq8(a00, a01);
            xs1 += sq8(a10, a11);
            bf16x8 ah0 = cvt8(a00, a01);
            bf16x8 ah1 = cvt8(a10, a11);
            uint4 b0 = B[s & 1][0], b1 = B[s & 1][1], b2 = B[s & 1][2], b3 = B[s & 1][3];
            if (s + 2 < 16) {
                #pragma unroll
                for (int t = 0; t < 4; ++t)
                    B[s & 1][t] = wp[((size_t)(s + 2) * 16 + t) * 64];
            }
            acc[0][0] = __builtin_amdgcn_mfma_f32_16x16x32_bf16(ah0, __builtin_bit_cast(bf16x8, b0), acc[0][0], 0, 0, 0);
            acc[1][0] = __builtin_amdgcn_mfma_f32_16x16x32_bf16(ah1, __builtin_bit_cast(bf16x8, b0), acc[1][0], 0, 0, 0);
            acc[0][1] = __builtin_amdgcn_mfma_f32_16x16x32_bf16(ah0, __builtin_bit_cast(bf16x8, b1), acc[0][1], 0, 0, 0);
            acc[1][1] = __builtin_amdgcn_mfma_f32_16x16x32_bf16(ah1, __builtin_bit_cast(bf16x8, b1), acc[1][1], 0, 0, 0);
            acc[0][2] = __builtin_amdgcn_mfma_f32_16x16x32_bf16(ah0, __builtin_bit_cast(bf16x8, b2), acc[0][2], 0, 0, 0);
            acc[1][2] = __builtin_amdgcn_mfma_f32_16x16x32_bf16(ah1, __builtin_bit_cast(bf16x8, b2), acc[1][2], 0, 0, 0);
            acc[0][3] = __builtin_amdgcn_mfma_f32_16x16x32_bf16(ah0, __builtin_bit_cast(bf16x8, b3), acc[0][3], 0, 0, 0);
            acc[1][3] = __builtin_amdgcn_mfma_f32_16x16x32_bf16(ah1, __builtin_bit_cast(bf16x8, b3), acc[1][3], 0, 0, 0);
        }
        if (kk < 7) BAR_TILE();
    }

    // xn2 (raw, unscaled): reduce across g-quarters; every wave identical, wave 0 publishes
    xs0 += __shfl_xor(xs0, 16); xs0 += __shfl_xor(xs0, 32);
    xs1 += __shfl_xor(xs1, 16); xs1 += __shfl_xor(xs1, 32);
    if (wave == 0 && lane < 16) { sxn2[lane] = xs0; sxn2[16 + lane] = xs1; }

    // per-wave partial ||mx_raw||^2 over this wave's 64 cols, per row
    #pragma unroll
    for (int hh = 0; hh < 2; ++hh) {
        #pragma unroll
        for (int r = 0; r < 4; ++r) {
            float p = 0.f;
            #pragma unroll
            for (int t = 0; t < 4; ++t) p += acc[hh][t][r] * acc[hh][t][r];
            p += __shfl_xor(p, 1);
            p += __shfl_xor(p, 2);
            p += __shfl_xor(p, 4);
            p += __shfl_xor(p, 8);
            if (rr == 0) sred[wave][hh * 16 + g * 4 + r] = p;
        }
    }
    __syncthreads();

    if (tid < BM) {
        const int r = tid;
        const float mx2 = sred[0][r] + sred[1][r] + sred[2][r] + sred[3][r];
        const float mxn = fmaxf(scale * sqrtf(mx2), EPSF);
        const float xn  = fmaxf(scale * sqrtf(sxn2[r]), EPSF);
        float ttv = tanhf(mxn / xn * artanh_clip(xn));
        float fc  = ttv * scale / mxn;     // applied to raw acc => scaled-mx direction
        if (mxn <= 1e-10f) { fc = 0.f; ttv = 0.f; }
        sfac[r] = fc;
        if (base + r < N) hnorm2[base + r] = ttv * ttv;
    }
    __syncthreads();

    #pragma unroll
    for (int hh = 0; hh < 2; ++hh) {
        #pragma unroll
        for (int r = 0; r < 4; ++r) {
            const int row_r = base + hh * 16 + g * 4 + r;
            if (row_r < N) {
                const float fc = sfac[hh * 16 + g * 4 + r];
                __half* hr = h + (size_t)row_r * NOUT + wave * 64 + rr;
                #pragma unroll
                for (int t = 0; t < 4; ++t) hr[t * 16] = __float2half(acc[hh][t][r] * fc);
            }
        }
    }
}

// K2 (R11-exact): sequential mobius scan. 16 lanes per row, 4 rows/wave;
// depth-4 gather prefetch; y2 via one load + shuffle broadcast; v_rcp.
__global__ __launch_bounds__(256) void aggregate_kernel(
    const __half* __restrict__ h, const float* __restrict__ hnorm2,
    const int* __restrict__ src, const float* __restrict__ bias,
    float* __restrict__ out, float scale, int N)
{
    const int wave = threadIdx.x >> 6;
    const int lane = threadIdx.x & 63;
    const int n0 = (blockIdx.x * 4 + wave) * 4;   // first of this wave's 4 rows
    if (n0 >= N) return;
    const int g = lane >> 4;      // row slot
    const int q = lane & 15;      // component group
    const int myrow = n0 + g;
    const bool rowok = myrow < N;

    size_t smax = (size_t)N * 16 - 1;
    size_t soff = (size_t)n0 * 16 + lane;
    int sidx = src[soff <= smax ? soff : smax];
    float y2v = hnorm2[sidx];

    int idx[16];
    float y2[16];
    #pragma unroll
    for (int j = 0; j < 16; ++j) {
        idx[j] = __shfl(sidx, (lane & 48) + j);
        y2[j]  = __shfl(y2v, (lane & 48) + j);
    }

    // c init from j=0; prefetch j=1..4 into slots 0..3
    uint4 cur0, cur1;
    {
        const uint4* hp = (const uint4*)(h + (size_t)idx[0] * NOUT);
        cur0 = hp[q * 2]; cur1 = hp[q * 2 + 1];
    }
    uint4 pa[4], pb[4];
    #pragma unroll
    for (int p = 0; p < 4; ++p) {
        const uint4* hp = (const uint4*)(h + (size_t)idx[p + 1] * NOUT);
        pa[p] = hp[q * 2]; pb[p] = hp[q * 2 + 1];
    }

    float c[16];
    unpack2h(cur0.x, c[0], c[1]);   unpack2h(cur0.y, c[2], c[3]);
    unpack2h(cur0.z, c[4], c[5]);   unpack2h(cur0.w, c[6], c[7]);
    unpack2h(cur1.x, c[8], c[9]);   unpack2h(cur1.y, c[10], c[11]);
    unpack2h(cur1.z, c[12], c[13]); unpack2h(cur1.w, c[14], c[15]);
    float c2 = y2[0];

    #pragma unroll
    for (int j = 1; j < 16; ++j) {
        const int slot = (j - 1) & 3;
        uint4 p0 = pa[slot], p1 = pb[slot];
        if (j + 4 < 16) {
            const uint4* hp = (const uint4*)(h + (size_t)idx[j + 4] * NOUT);
            pa[slot] = hp[q * 2]; pb[slot] = hp[q * 2 + 1];
        }
        float yv[16];
        unpack2h(p0.x, yv[0], yv[1]);   unpack2h(p0.y, yv[2], yv[3]);
        unpack2h(p0.z, yv[4], yv[5]);   unpack2h(p0.w, yv[6], yv[7]);
        unpack2h(p1.x, yv[8], yv[9]);   unpack2h(p1.y, yv[10], yv[11]);
        unpack2h(p1.z, yv[12], yv[13]); unpack2h(p1.w, yv[14], yv[15]);

        float xp = 0.f;
        #pragma unroll
        for (int i = 0; i < 16; ++i) xp = fmaf(c[i], yv[i], xp);
        xp += __shfl_xor(xp, 1);
        xp += __shfl_xor(xp, 2);
        xp += __shfl_xor(xp, 4);
        xp += __shfl_xor(xp, 8);
        const float xy = xp;

        const float A = 1.f + 2.f * xy + y2[j];
        const float B = 1.f - c2;
        const float den = fmaxf(1.f + 2.f * xy + c2 * y2[j], EPSF);
        const float inv = __builtin_amdgcn_rcpf(den);
        #pragma unroll
        for (int i = 0; i < 16; ++i) c[i] = (fmaf(A, c[i], B * yv[i])) * inv;
        c2 = fmaxf((A * A * c2 + 2.f * A * B * xy + B * B * y2[j]) * (inv * inv), 0.f);
    }

    // rst *= scale
    #pragma unroll
    for (int i = 0; i < 16; ++i) c[i] *= scale;
    c2 *= scale * scale;

    // mobius_add(rst, bias)
    float bv[16];
    {
        const float4* bp = (const float4*)(bias + q * 16);
        float4 b0 = bp[0], b1 = bp[1], b2 = bp[2], b3 = bp[3];
        bv[0]=b0.x; bv[1]=b0.y; bv[2]=b0.z; bv[3]=b0.w;
        bv[4]=b1.x; bv[5]=b1.y; bv[6]=b1.z; bv[7]=b1.w;
        bv[8]=b2.x; bv[9]=b2.y; bv[10]=b2.z; bv[11]=b2.w;
        bv[12]=b3.x; bv[13]=b3.y; bv[14]=b3.z; bv[15]=b3.w;
    }
    float bp_ = 0.f, xp_ = 0.f;
    #pragma unroll
    for (int i = 0; i < 16; ++i) { bp_ = fmaf(bv[i], bv[i], bp_); xp_ = fmaf(c[i], bv[i], xp_); }
    bp_ += __shfl_xor(bp_, 1); xp_ += __shfl_xor(xp_, 1);
    bp_ += __shfl_xor(bp_, 2); xp_ += __shfl_xor(xp_, 2);
    bp_ += __shfl_xor(bp_, 4); xp_ += __shfl_xor(xp_, 4);
    bp_ += __shfl_xor(bp_, 8); xp_ += __shfl_xor(xp_, 8);
    const float bb = bp_, xy = xp_;

    const float A = 1.f + 2.f * xy + bb;
    const float B = 1.f - c2;
    const float den = fmaxf(1.f + 2.f * xy + c2 * bb, EPSF);
    const float inv = 1.f / den;
    float r4[16];
    #pragma unroll
    for (int i = 0; i < 16; ++i) r4[i] = fmaf(A, c[i], B * bv[i]) * inv;
    const float rn2 = fmaxf((A * A * c2 + 2.f * A * B * xy + B * B * bb) * (inv * inv), 0.f);

    // expmap0(relu(logmap0(.)))
    const float rn = fmaxf(sqrtf(rn2), EPSF);
    const float lf = artanh_clip(rn) / rn;
    float u[16];
    float up = 0.f;
    #pragma unroll
    for (int i = 0; i < 16; ++i) { u[i] = fmaxf(r4[i] * lf, 0.f); up = fmaf(u[i], u[i], up); }
    up += __shfl_xor(up, 1);
    up += __shfl_xor(up, 2);
    up += __shfl_xor(up, 4);
    up += __shfl_xor(up, 8);
    const float un = fmaxf(sqrtf(up), EPSF);
    const float ef = tanhf(un) / un;

    if (rowok) {
        float* op = out + (size_t)myrow * NOUT + q * 16;
        float4 o;
        o.x = u[0]*ef;  o.y = u[1]*ef;  o.z = u[2]*ef;  o.w = u[3]*ef;  ((float4*)op)[0] = o;
        o.x = u[4]*ef;  o.y = u[5]*ef;  o.z = u[6]*ef;  o.w = u[7]*ef;  ((float4*)op)[1] = o;
        o.x = u[8]*ef;  o.y = u[9]*ef;  o.z = u[10]*ef; o.w = u[11]*ef; ((float4*)op)[2] = o;
        o.x = u[12]*ef; o.y = u[13]*ef; o.z = u[14]*ef; o.w = u[15]*ef; ((float4*)op)[3] = o;
    }
}

extern "C" void kernel_launch(void* const* d_in, const int* in_sizes, int n_in,
                              void* d_out, int out_size, void* d_ws, size_t ws_size,
                              hipStream_t stream) {
    const float* feat   = (const float*)d_in[0];
    const float* weight = (const float*)d_in[1];
    const float* bias   = (const float*)d_in[2];
    const int*   src    = (const int*)d_in[3];

    const int OUT = in_sizes[2];            // 256
    const int IN  = in_sizes[1] / OUT;      // 512
    const int N   = in_sizes[0] / IN;       // 20000
    const int DEG = in_sizes[3] / N;        // 16
    (void)IN; (void)DEG; (void)out_size; (void)ws_size; (void)n_in;

    const float scale = 1.0f / sqrtf((float)DEG);

    // ws layout: h fp16 (N*256*2 B) | hnorm2 (N f32) | Wp (256 KB)
    char* ws = (char*)d_ws;
    __half* h     = (__half*)ws;
    float* hnorm2 = (float*)(ws + (size_t)N * NOUT * 2);
    unsigned int* Wp = (unsigned int*)(ws + (size_t)N * NOUT * 2 + (size_t)N * 4);

    float* out = (float*)d_out;

    const int nbm = (N + BM - 1) / BM;      // 625

    hipLaunchKernelGGL(prep_w_kernel, dim3(256), dim3(64), 0, stream,
                       weight, Wp);
    hipLaunchKernelGGL(gemm_mobius_kernel, dim3(nbm), dim3(256), 0, stream,
                       feat, (const uint4*)Wp, h, hnorm2, scale, N);
    hipLaunchKernelGGL(aggregate_kernel, dim3((N + 15) / 16), dim3(256), 0, stream,
                       h, hnorm2, src, bias, out, scale, N);
}